// Round 1
// baseline (425.047 us; speedup 1.0000x reference)
//
#include <hip/hip_runtime.h>

typedef __attribute__((ext_vector_type(4))) float          f32x4;
typedef __attribute__((ext_vector_type(8))) short          s16x8;
typedef __attribute__((ext_vector_type(4))) unsigned short u16x4;
typedef __attribute__((ext_vector_type(8))) unsigned short u16x8;

#define MFMA_BF16(a, b, c) __builtin_amdgcn_mfma_f32_16x16x32_bf16((a), (b), (c), 0, 0, 0)

static constexpr int Bb = 2, Ss = 2048, Ee = 1024, Hh = 16, Dd = 64;
static constexpr int Mtok = Bb * Ss; // 4096

// fp32 -> bf16 round-to-nearest-even (inputs are finite; no NaN handling needed)
__device__ __forceinline__ unsigned short f2b(float f) {
    unsigned u = __builtin_bit_cast(unsigned, f);
    u += 0x7fffu + ((u >> 16) & 1u);
    return (unsigned short)(u >> 16);
}

// ---------------------------------------------------------------------------
// Generic 128x128-tile GEMM: C[m][n] = sum_k A[m][k] * W[n][k] + bias[n]
// A is fp32 or bf16 (A_BF16), W/bias fp32 (converted to bf16 while staging),
// C is bf16 or fp32 (OUT_BF16). M=4096, N=K=1024 fixed.
// Block: 256 threads = 4 waves, each wave computes 64x64 via 4x4 MFMA tiles.
// ---------------------------------------------------------------------------
template <bool A_BF16, bool OUT_BF16>
__device__ __forceinline__ void gemm_body(const void* __restrict__ Av,
                                          const float* __restrict__ W,
                                          const float* __restrict__ bias,
                                          void* __restrict__ Cv)
{
    __shared__ __align__(16) unsigned short Al[128 * 32]; // [m][k] k-contig
    __shared__ __align__(16) unsigned short Bl[128 * 32]; // [n][k] k-contig

    const int tid  = threadIdx.x;
    const int lane = tid & 63;
    const int wid  = tid >> 6;
    const int quad = lane >> 4;
    const int lr   = lane & 15;
    const int wr   = (wid >> 1) * 64;
    const int wc   = (wid & 1) * 64;
    const int m0   = blockIdx.y * 128;
    const int n0   = blockIdx.x * 128;

    f32x4 acc[4][4];
#pragma unroll
    for (int i = 0; i < 4; i++)
#pragma unroll
        for (int j = 0; j < 4; j++) acc[i][j] = (f32x4){0.f, 0.f, 0.f, 0.f};

    for (int ks = 0; ks < 1024; ks += 32) {
        __syncthreads();
        // stage A-tile (128x32) and W-tile (128x32); 1024 4-elem chunks each
#pragma unroll
        for (int i = 0; i < 4; i++) {
            int c   = tid + i * 256;
            int row = c >> 3;
            int kq  = (c & 7) * 4;
            u16x4 bv;
            if (A_BF16) {
                bv = *(const u16x4*)((const unsigned short*)Av +
                                     (size_t)(m0 + row) * 1024 + ks + kq);
            } else {
                f32x4 av = *(const f32x4*)((const float*)Av +
                                           (size_t)(m0 + row) * 1024 + ks + kq);
                bv = (u16x4){f2b(av[0]), f2b(av[1]), f2b(av[2]), f2b(av[3])};
            }
            *(u16x4*)&Al[row * 32 + kq] = bv;

            f32x4 wv = *(const f32x4*)(W + (size_t)(n0 + row) * 1024 + ks + kq);
            *(u16x4*)&Bl[row * 32 + kq] =
                (u16x4){f2b(wv[0]), f2b(wv[1]), f2b(wv[2]), f2b(wv[3])};
        }
        __syncthreads();

        s16x8 af[4], bf[4];
#pragma unroll
        for (int t = 0; t < 4; t++) {
            af[t] = *(const s16x8*)&Al[(wr + t * 16 + lr) * 32 + quad * 8];
            bf[t] = *(const s16x8*)&Bl[(wc + t * 16 + lr) * 32 + quad * 8];
        }
#pragma unroll
        for (int mt = 0; mt < 4; mt++)
#pragma unroll
            for (int nt = 0; nt < 4; nt++)
                acc[mt][nt] = MFMA_BF16(af[mt], bf[nt], acc[mt][nt]);
    }

#pragma unroll
    for (int mt = 0; mt < 4; mt++)
#pragma unroll
        for (int nt = 0; nt < 4; nt++) {
            int   col  = n0 + wc + nt * 16 + lr;
            float bcol = bias[col];
#pragma unroll
            for (int r = 0; r < 4; r++) {
                int   row = m0 + wr + mt * 16 + quad * 4 + r;
                float v   = acc[mt][nt][r] + bcol;
                if (OUT_BF16)
                    ((unsigned short*)Cv)[(size_t)row * 1024 + col] = f2b(v);
                else
                    ((float*)Cv)[(size_t)row * 1024 + col] = v;
            }
        }
}

struct ProjArgs {
    const float* A[3];
    const float* W[3];
    const float* b[3];
    unsigned short* C[3];
};

__global__ __launch_bounds__(256) void proj_gemm(ProjArgs pa)
{
    int z = blockIdx.z;
    gemm_body<false, true>(pa.A[z], pa.W[z], pa.b[z], pa.C[z]);
}

__global__ __launch_bounds__(256) void out_gemm(const unsigned short* __restrict__ A,
                                                const float* __restrict__ W,
                                                const float* __restrict__ bias,
                                                float* __restrict__ C)
{
    gemm_body<true, false>(A, W, bias, C);
}

// ---------------------------------------------------------------------------
// Flash attention: one block = (b, h, 64 q-rows); 4 waves x 16 q-rows each.
// Iterates keys in 64-wide tiles with online softmax. Q/K/V are bf16 in
// [B*S, E] layout (head h occupies cols h*64..h*64+63).
// Masked scores are set to exactly -1e10 (matches reference set-not-add);
// fully-masked rows degrade to uniform weights automatically.
// ---------------------------------------------------------------------------
__global__ __launch_bounds__(256)
void flash_attn(const unsigned short* __restrict__ Q,
                const unsigned short* __restrict__ K,
                const unsigned short* __restrict__ V,
                const int* __restrict__ mask,
                unsigned short* __restrict__ O)
{
    __shared__ __align__(16) unsigned short Kl[64 * 64];      // [k][d]
    __shared__ __align__(16) unsigned short Vt[64 * 64];      // [d][k] transposed
    __shared__ __align__(16) unsigned short Pl[4][16 * 64];   // per-wave P tile
    __shared__ int mk[2048];

    const int b  = blockIdx.z;
    const int h  = blockIdx.y;
    const int q0 = blockIdx.x * 64;

    const int tid  = threadIdx.x;
    const int lane = tid & 63;
    const int wid  = tid >> 6;
    const int quad = lane >> 4;
    const int lr   = lane & 15;

    for (int i = tid; i < 2048; i += 256) mk[i] = mask[b * 2048 + i];

    // Q fragments (A-operand layout): row m = lr, k = quad*8 + j (+32 for c=1)
    const size_t qbase = (size_t)(b * 2048 + q0 + wid * 16 + lr) * 1024 + h * 64;
    s16x8 qf0 = *(const s16x8*)(Q + qbase + quad * 8);
    s16x8 qf1 = *(const s16x8*)(Q + qbase + 32 + quad * 8);

    __syncthreads();
    int mq[4];
#pragma unroll
    for (int r = 0; r < 4; r++) mq[r] = mk[q0 + wid * 16 + quad * 4 + r];

    float mrun[4], lrun[4];
#pragma unroll
    for (int r = 0; r < 4; r++) { mrun[r] = -__builtin_inff(); lrun[r] = 0.f; }
    f32x4 accO[4];
#pragma unroll
    for (int t = 0; t < 4; t++) accO[t] = (f32x4){0.f, 0.f, 0.f, 0.f};

    for (int kt = 0; kt < 2048; kt += 64) {
        __syncthreads();
        // stage K-tile [64][64] and transposed V-tile [64][64]
#pragma unroll
        for (int i = 0; i < 2; i++) {
            int c  = tid + i * 256;     // 0..511
            int kr = c >> 3;
            int d8 = (c & 7) * 8;
            size_t g = (size_t)(b * 2048 + kt + kr) * 1024 + h * 64 + d8;
            u16x8 kv = *(const u16x8*)(K + g);
            *(u16x8*)&Kl[kr * 64 + d8] = kv;
            u16x8 vv = *(const u16x8*)(V + g);
#pragma unroll
            for (int j = 0; j < 8; j++) Vt[(d8 + j) * 64 + kr] = vv[j];
        }
        __syncthreads();

        // scores: S[16 q][64 k] per wave, in C-layout (row=quad*4+r, col=lr)
        float sc[4][4];
#pragma unroll
        for (int ct = 0; ct < 4; ct++) {
            f32x4 s = (f32x4){0.f, 0.f, 0.f, 0.f};
            s = MFMA_BF16(qf0, *(const s16x8*)&Kl[(ct * 16 + lr) * 64 + quad * 8], s);
            s = MFMA_BF16(qf1, *(const s16x8*)&Kl[(ct * 16 + lr) * 64 + 32 + quad * 8], s);
            int padk = (mk[kt + ct * 16 + lr] == 0);
#pragma unroll
            for (int r = 0; r < 4; r++)
                sc[ct][r] = (padk || (mq[r] == 0)) ? -1e10f : s[r] * 0.125f;
        }

        // online softmax per q-row (row spread across the 16 lanes of a quad)
#pragma unroll
        for (int r = 0; r < 4; r++) {
            float tm = fmaxf(fmaxf(sc[0][r], sc[1][r]), fmaxf(sc[2][r], sc[3][r]));
#pragma unroll
            for (int d = 1; d < 16; d <<= 1) tm = fmaxf(tm, __shfl_xor(tm, d, 64));
            float mnew  = fmaxf(mrun[r], tm);
            float alpha = __expf(mrun[r] - mnew);
            mrun[r] = mnew;
            float ps = 0.f;
#pragma unroll
            for (int ct = 0; ct < 4; ct++) {
                float p = __expf(sc[ct][r] - mnew);
                sc[ct][r] = p;
                ps += p;
            }
#pragma unroll
            for (int d = 1; d < 16; d <<= 1) ps += __shfl_xor(ps, d, 64);
            lrun[r] = lrun[r] * alpha + ps;
#pragma unroll
            for (int t = 0; t < 4; t++) accO[t][r] *= alpha;
        }

        // P: C-layout regs -> LDS -> A-operand layout (per-wave region)
#pragma unroll
        for (int ct = 0; ct < 4; ct++)
#pragma unroll
            for (int r = 0; r < 4; r++)
                Pl[wid][(quad * 4 + r) * 64 + ct * 16 + lr] = f2b(sc[ct][r]);

        s16x8 pf0 = *(const s16x8*)&Pl[wid][lr * 64 + quad * 8];
        s16x8 pf1 = *(const s16x8*)&Pl[wid][lr * 64 + 32 + quad * 8];
#pragma unroll
        for (int dt = 0; dt < 4; dt++) {
            accO[dt] = MFMA_BF16(pf0, *(const s16x8*)&Vt[(dt * 16 + lr) * 64 + quad * 8], accO[dt]);
            accO[dt] = MFMA_BF16(pf1, *(const s16x8*)&Vt[(dt * 16 + lr) * 64 + 32 + quad * 8], accO[dt]);
        }
    }

    // epilogue: normalize and store bf16 attn output [B*S, E]
#pragma unroll
    for (int dt = 0; dt < 4; dt++)
#pragma unroll
        for (int r = 0; r < 4; r++) {
            float val = accO[dt][r] / lrun[r];
            int   q   = q0 + wid * 16 + quad * 4 + r;
            O[(size_t)(b * 2048 + q) * 1024 + h * 64 + dt * 16 + lr] = f2b(val);
        }
}

// ---------------------------------------------------------------------------
extern "C" void kernel_launch(void* const* d_in, const int* in_sizes, int n_in,
                              void* d_out, int out_size, void* d_ws, size_t ws_size,
                              hipStream_t stream)
{
    const float* query = (const float*)d_in[0];
    const float* key_  = (const float*)d_in[1];
    const float* value = (const float*)d_in[2];
    const int*   mask  = (const int*)d_in[3];
    const float* Wq    = (const float*)d_in[4];
    const float* bq    = (const float*)d_in[5];
    const float* Wk    = (const float*)d_in[6];
    const float* bk    = (const float*)d_in[7];
    const float* Wv    = (const float*)d_in[8];
    const float* bv    = (const float*)d_in[9];
    const float* Wo    = (const float*)d_in[10];
    const float* bo    = (const float*)d_in[11];
    float* out = (float*)d_out;

    // workspace: Q, K, V, attn-out as bf16 [4096,1024] each = 32 MB total
    unsigned short* Qb = (unsigned short*)d_ws;
    unsigned short* Kb = Qb + (size_t)Mtok * Ee;
    unsigned short* Vb = Kb + (size_t)Mtok * Ee;
    unsigned short* Ab = Vb + (size_t)Mtok * Ee;

    ProjArgs pa;
    pa.A[0] = query; pa.A[1] = key_; pa.A[2] = value;
    pa.W[0] = Wq;    pa.W[1] = Wk;   pa.W[2] = Wv;
    pa.b[0] = bq;    pa.b[1] = bk;   pa.b[2] = bv;
    pa.C[0] = Qb;    pa.C[1] = Kb;   pa.C[2] = Vb;

    proj_gemm<<<dim3(8, 32, 3), 256, 0, stream>>>(pa);
    flash_attn<<<dim3(Ss / 64, Hh, Bb), 256, 0, stream>>>(Qb, Kb, Vb, mask, Ab);
    out_gemm<<<dim3(8, 32, 1), 256, 0, stream>>>(Ab, Wo, bo, out);
}